// Round 9
// baseline (66.147 us; speedup 1.0000x reference)
//
#include <hip/hip_runtime.h>
#include <math.h>

// x: (64,1,128,128) f32 -> K=2 conv -> 127x127 patches/image.
// Quantum circuit collapses analytically (CNOTs couple only (0,1),(2,3); Z0
// readout => wires 2,3 trace out; t0=x[i,j], t1=x[i,j+1]):
//   q = k0 + k1 cos t0 + k2 cos t1 + k3 cos t0 cos t1 + k4 sin t0 sin t1
//
// R9: SINGLE dispatch, one block per image (64 blocks x 1024 threads).
//  * block reduction replaces the stage-2 kernel entirely -> out[img] direct
//  * no cross-block sync anywhere (R5 spin: +50us, R6 counter RMW: +45us)
//  * float4 loads; one sincos per element (quantum term needs only each
//    patch's top row); neighbor cos/sin via __shfl_down (lanes with
//    col0==124 never need the cross-row neighbor)
//  * conv = position-weighted single pass: weight(r,c) =
//    ([r<127]w0+[r>0]w2)*[c<127] + ([r<127]w1+[r>0]w3)*[c>0]
//  * coeffs on tid0 only -> LDS -> barrier (R7->R8 lesson: redundant
//    per-thread uniform math cost ~3us)

#define NP (127 * 127)
#define NB 64
#define BLK 1024
#define PASSES 4            // 4096 float4 per image / 1024 threads

__device__ __forceinline__ void circuit_coeffs(const float* __restrict__ ry,
                                               float k[5]) {
    float U[4][4] = {{1,0,0,0},{0,1,0,0},{0,0,1,0},{0,0,0,1}};
    for (int l = 0; l < 2; ++l) {
        float s0, c0, s1, c1;
        __sincosf(0.5f * ry[l*4+0], &s0, &c0);
        __sincosf(0.5f * ry[l*4+1], &s1, &c1);
        for (int q1 = 0; q1 < 2; ++q1)
            for (int c = 0; c < 4; ++c) {
                float a = U[q1][c], d = U[2+q1][c];
                U[q1][c]   = c0*a - s0*d;
                U[2+q1][c] = s0*a + c0*d;
            }
        for (int m = 0; m < 2; ++m)
            for (int c = 0; c < 4; ++c) {
                float a = U[2*m][c], d = U[2*m+1][c];
                U[2*m][c]   = c1*a - s1*d;
                U[2*m+1][c] = s1*a + c1*d;
            }
        for (int c = 0; c < 4; ++c) { float t = U[2][c]; U[2][c] = U[3][c]; U[3][c] = t; }
    }
    float pA=0, pB=0, pC=0, pD=0, pAD=0, pBC=0;
    for (int r = 0; r < 4; ++r) {
        float g = (r < 2) ? 1.f : -1.f;
        pA  += g * U[r][0] * U[r][0];
        pB  += g * U[r][1] * U[r][1];
        pC  += g * U[r][2] * U[r][2];
        pD  += g * U[r][3] * U[r][3];
        pAD += g * U[r][0] * U[r][3];
        pBC += g * U[r][1] * U[r][2];
    }
    k[0] = 0.25f * (pA + pB + pC + pD);
    k[1] = 0.25f * (pA + pB - pC - pD);
    k[2] = 0.25f * (pA - pB + pC - pD);
    k[3] = 0.25f * (pA - pB - pC + pD);
    k[4] = 0.50f * (pBC - pAD);
}

__global__ __launch_bounds__(BLK) void image_kernel(
    const float* __restrict__ x,
    const float* __restrict__ conv_w,
    const float* __restrict__ conv_b,
    const float* __restrict__ ry,
    const float* __restrict__ head_w,
    const float* __restrict__ head_b,
    float* __restrict__ out)           // 64 floats
{
    __shared__ float sk[4];            // hw1-prescaled k1..k4
    __shared__ float red[BLK / 64];    // 16 wave partials

    const int tid  = threadIdx.x;
    const int lane = tid & 63;
    const int wave = tid >> 6;
    const int img  = blockIdx.x;
    const int col0 = (tid & 31) << 2;  // 0,4,...,124 (pass-invariant)

    float cconst = 0.f;                // live only in tid 0
    if (tid == 0) {
        float k[5];
        circuit_coeffs(ry, k);
        const float hw1 = head_w[1];
        sk[0] = hw1 * k[1]; sk[1] = hw1 * k[2];
        sk[2] = hw1 * k[3]; sk[3] = hw1 * k[4];
        cconst = head_w[0] * conv_b[0] + hw1 * k[0] + head_b[0];
    }
    __syncthreads();

    const float hw0 = head_w[0];
    const float w0 = hw0 * conv_w[0], w1 = hw0 * conv_w[1];
    const float w2 = hw0 * conv_w[2], w3 = hw0 * conv_w[3];
    const float k1 = sk[0], k2 = sk[1], k3 = sk[2], k4 = sk[3];

    const float4* __restrict__ xi = (const float4*)(x + (size_t)img * 16384);

    float acc = 0.f;
#pragma unroll
    for (int p = 0; p < PASSES; ++p) {
        const int idx = p * BLK + tid;       // 0..4095 float4 index
        const int row = idx >> 5;            // 0..127
        const float4 e = xi[idx];

        const float P = (row < 127 ? w0 : 0.f) + (row > 0 ? w2 : 0.f);
        const float Q = (row < 127 ? w1 : 0.f) + (row > 0 ? w3 : 0.f);
        const float PQ = P + Q;

        acc += e.x * (col0 == 0 ? P : PQ)
             + e.y * PQ
             + e.z * PQ
             + e.w * (col0 == 124 ? Q : PQ);

        float s0,c0,s1,c1,s2,c2,s3,c3;
        __sincosf(e.x, &s0, &c0);
        __sincosf(e.y, &s1, &c1);
        __sincosf(e.z, &s2, &c2);
        __sincosf(e.w, &s3, &c3);
        const float cn = __shfl_down(c0, 1, 64);  // lane+1's first cos
        const float sn = __shfl_down(s0, 1, 64);  // (same row when used)
        if (row < 127) {
            acc += k1 * c0 + k2 * c1 + k3 * c0 * c1 + k4 * s0 * s1;
            acc += k1 * c1 + k2 * c2 + k3 * c1 * c2 + k4 * s1 * s2;
            acc += k1 * c2 + k2 * c3 + k3 * c2 * c3 + k4 * s2 * s3;
            if (col0 < 124)
                acc += k1 * c3 + k2 * cn + k3 * c3 * cn + k4 * s3 * sn;
        }
    }

    // wave reduce -> LDS -> wave-0 reduce
    for (int off = 32; off > 0; off >>= 1)
        acc += __shfl_down(acc, off, 64);
    if (lane == 0) red[wave] = acc;
    __syncthreads();
    if (wave == 0) {
        float v = (lane < BLK / 64) ? red[lane] : 0.f;
        for (int off = 8; off > 0; off >>= 1)
            v += __shfl_down(v, off, 64);
        if (tid == 0)
            out[img] = v * (1.0f / NP) + cconst;
    }
}

extern "C" void kernel_launch(void* const* d_in, const int* in_sizes, int n_in,
                              void* d_out, int out_size, void* d_ws, size_t ws_size,
                              hipStream_t stream) {
    const float* x      = (const float*)d_in[0];
    const float* conv_w = (const float*)d_in[1];
    const float* conv_b = (const float*)d_in[2];
    const float* ry     = (const float*)d_in[3];
    const float* head_w = (const float*)d_in[4];
    const float* head_b = (const float*)d_in[5];
    float* out = (float*)d_out;

    image_kernel<<<NB, BLK, 0, stream>>>(x, conv_w, conv_b, ry, head_w,
                                         head_b, out);
}